// Round 13
// baseline (260.008 us; speedup 1.0000x reference)
//
#include <hip/hip_runtime.h>
#include <hip/hip_bf16.h>
#include <math.h>

typedef __attribute__((ext_vector_type(8))) short short8;   // 8 bf16 = one MFMA A/B frag
typedef __attribute__((ext_vector_type(4))) short bf16x4;   // 4 bf16 (8B)
typedef __attribute__((ext_vector_type(4))) float f32x4;    // MFMA C/D frag

#define MFMA16x16x32(A,B,C) __builtin_amdgcn_mfma_f32_16x16x32_bf16((A),(B),(C),0,0,0)
#define AS1(p) ((const __attribute__((address_space(1))) void*)(p))
#define AS3(p) ((__attribute__((address_space(3))) void*)(p))
#define WAITVM0() asm volatile("s_waitcnt vmcnt(0)" ::: "memory")
#define WAITVM2() asm volatile("s_waitcnt vmcnt(2)" ::: "memory")
#define WAITVM4() asm volatile("s_waitcnt vmcnt(4)" ::: "memory")
#define LGKM0()   asm volatile("s_waitcnt lgkmcnt(0)" ::: "memory")
// barrier that does NOT drain vmcnt
#define BAR_LGKM() do { LGKM0(); __builtin_amdgcn_s_barrier(); } while (0)

__device__ __forceinline__ short f2b(float x) {
  __hip_bfloat16 h = __float2bfloat16(x);
  short s; __builtin_memcpy(&s, &h, 2); return s;
}
__device__ __forceinline__ float b2f(short s) {
  __hip_bfloat16 h; __builtin_memcpy(&h, &s, 2); return __bfloat162float(h);
}

// ---------------------------------------------------------------------------
// prep: blocks 0..63 pack the 4 weights [512][512] fp32 -> bf16 MFMA B-frag
// order: elem index = ((kf*32 + nf)*64 + lane)*8 + jj, where lane holds
// (n = nf*16 + lane%16, k = kf*32 + 8*(lane/16) + jj). block 64: softplus(scale).
// ---------------------------------------------------------------------------
__global__ __launch_bounds__(256)
void prep_kernel(const float* __restrict__ Wq, const float* __restrict__ Wk,
                 const float* __restrict__ Wv, const float* __restrict__ Wp,
                 const float* __restrict__ scale,
                 short* __restrict__ wpack, float* __restrict__ spls)
{
  const int b = blockIdx.x;
  const int t = threadIdx.x;
  if (b == 64) {
    for (int i = t; i < 512; i += 256) {
      float x = scale[i];
      spls[i] = (x > 20.f) ? x : log1pf(expf(x));
    }
    return;
  }
  const float* Ws[4] = {Wq, Wk, Wv, Wp};
  const int w = b >> 4, kf16 = b & 15;
  const float* W = Ws[w];
  short* dst = wpack + (size_t)w * (512 * 512);
  __shared__ short lds[32 * 512];
  for (int i = 0; i < 64; ++i) {
    int idx = i * 256 + t;              // 0..16383
    int r = idx >> 9, c = idx & 511;
    lds[idx] = f2b(W[(size_t)(kf16 * 32 + r) * 512 + c]);
  }
  __syncthreads();
  for (int s = 0; s < 8; ++s) {
    int slot = s * 256 + t;             // 0..2047 = 32 nfrags x 64 lanes
    int nf = slot >> 6, l = slot & 63;
    int n = nf * 16 + (l & 15);
    int k0 = 8 * (l >> 4);
    short8 v;
#pragma unroll
    for (int jj = 0; jj < 8; ++jj) v[jj] = lds[(k0 + jj) * 512 + n];
    *(short8*)(dst + ((size_t)(kf16 * 32 + nf) * 64 + l) * 8) = v;
  }
}

// ---------------------------------------------------------------------------
// gemm128: fused q/k/v projections, 128x128 tiles (m97-style pipeline).
// 256 thr = 4 waves (2x2), wave owns 64x64 (4x4 acc). BK=32, 16 steps.
// B (frag-packed wpack panel, 8KB/step) DMA'd via global_load_lds, dbuf,
// counted vmcnt (4/2, never 0 mid-loop), ONE barrier per step. A (fp32)
// reg-staged coalesced -> cvt -> frag-packed LDS dbuf; all k-loop ds_reads
// are stride-1 b128 (conflict-free). LDS 32KB + 2KB -> 4 blocks/CU.
// mode 0/1 (q/k): epilogue y=(relu+eps)/spls; write y bf16 row-major to
// ybuf + atomicAdd per-row sum(y^2),sum(y^6). mode 2 (v): pack write.
// ---------------------------------------------------------------------------
__global__ __launch_bounds__(256)
void gemm128(const float* __restrict__ Aq, const float* __restrict__ Ak,
             const float* __restrict__ Av, const short* __restrict__ wpack,
             const float* __restrict__ spls,
             short* __restrict__ yq, short* __restrict__ yk,
             short* __restrict__ vpk,
             float* __restrict__ gp2q, float* __restrict__ gp6q,
             float* __restrict__ gp2k, float* __restrict__ gp6k)
{
  __shared__ __align__(128) char smem[32768]; // A dbuf [0,16K), B dbuf [16K,32K); bounce overlay
  __shared__ float pn2[2][128];
  __shared__ float pn6[2][128];
  const int t = threadIdx.x;
  const int lane = t & 63;
  const int wid = t >> 6;               // 0..3
  const int wr = wid >> 1;              // row half
  const int wc = wid & 1;               // col half
  const int g = lane >> 4;
  const int cl = lane & 15;
  const int bid = blockIdx.x;
  const int mode = bid % 3;
  const int rem = bid / 3;
  const int cblk = rem & 3;
  const int rblk = rem >> 2;            // 0..255
  const int rb = rblk << 7;
  const int cb = cblk << 7;

  const float* Af = (mode == 0) ? Aq : (mode == 1) ? Ak : Av;
  const char* wsrc = (const char*)(wpack + (size_t)mode * (512 * 512));
  char* Ab0 = smem;
  char* Ab1 = smem + 8192;
  char* Bb0 = smem + 16384;
  char* Bb1 = smem + 24576;

  f32x4 ra[4];
  auto loadA = [&](int kf) {
#pragma unroll
    for (int i = 0; i < 4; ++i) {
      int chunk = i * 256 + t;          // 0..1023, 16B fp32 each
      int row = chunk >> 3, sub = chunk & 7;
      ra[i] = *(const f32x4*)(Af + (size_t)(rb + row) * 512 + kf * 32 + sub * 4);
    }
  };
  auto writeA = [&](char* dst) {
#pragma unroll
    for (int i = 0; i < 4; ++i) {
      int chunk = i * 256 + t;
      int row = chunk >> 3, sub = chunk & 7;
      bf16x4 v;
      v[0] = f2b(ra[i][0]); v[1] = f2b(ra[i][1]);
      v[2] = f2b(ra[i][2]); v[3] = f2b(ra[i][3]);
      *(bf16x4*)(dst + (row >> 4) * 1024 + ((sub >> 1) * 16 + (row & 15)) * 16 + (sub & 1) * 8) = v;
    }
  };
  auto stageB = [&](int kf, char* dst) {
    const char* src = wsrc + ((size_t)(kf * 32 + cblk * 8)) * 1024;
    const int off = t * 16;
    __builtin_amdgcn_global_load_lds(AS1(src + off),        AS3(dst + off),        16, 0, 0);
    __builtin_amdgcn_global_load_lds(AS1(src + 4096 + off), AS3(dst + 4096 + off), 16, 0, 0);
  };

  f32x4 zero4 = {0.f, 0.f, 0.f, 0.f};
  f32x4 acc[4][4];
#pragma unroll
  for (int rf = 0; rf < 4; ++rf)
#pragma unroll
    for (int cf = 0; cf < 4; ++cf) acc[rf][cf] = zero4;

  // ---- prologue: rA(0), B(0)-DMA; A(0) -> Ab0 ----
  loadA(0);
  stageB(0, Bb0);
  WAITVM2();                  // rA(0) done, B(0) stays in flight
  writeA(Ab0);
  LGKM0();

  // ---- main loop: kf = 0..14; step kf computes slice kf ----
  for (int kf = 0; kf < 15; ++kf) {
    char* Ac = (kf & 1) ? Ab1 : Ab0;
    char* An = (kf & 1) ? Ab0 : Ab1;
    char* Bc = (kf & 1) ? Bb1 : Bb0;
    char* Bn = (kf & 1) ? Bb0 : Bb1;
    loadA(kf + 1);            // 4 vm: rA for next slice
    WAITVM4();                // B(kf) landed (4 newer rA allowed in flight)
    __builtin_amdgcn_s_barrier();   // all waves: A(kf), B(kf) visible
    stageB(kf + 1, Bn);       // safe post-barrier (Bn last read at step kf-1)
    short8 bfr[4], af[4];
#pragma unroll
    for (int cf = 0; cf < 4; ++cf)
      bfr[cf] = *(const short8*)(Bc + ((wc * 4 + cf) * 64 + lane) * 16);
#pragma unroll
    for (int rf = 0; rf < 4; ++rf)
      af[rf] = *(const short8*)(Ac + ((wr * 4 + rf) * 64 + lane) * 16);
    __builtin_amdgcn_s_setprio(1);
#pragma unroll
    for (int rf = 0; rf < 4; ++rf)
#pragma unroll
      for (int cf = 0; cf < 4; ++cf)
        acc[rf][cf] = MFMA16x16x32(af[rf], bfr[cf], acc[rf][cf]);
    __builtin_amdgcn_s_setprio(0);
    WAITVM2();                // rA(kf+1) done (B(kf+1) DMA stays in flight)
    writeA(An);
    LGKM0();
  }
  // ---- peeled kf = 15 ----
  {
    WAITVM0();
    __builtin_amdgcn_s_barrier();
    char* Ac = Ab1;           // 15&1 = 1
    char* Bc = Bb1;
    short8 bfr[4], af[4];
#pragma unroll
    for (int cf = 0; cf < 4; ++cf)
      bfr[cf] = *(const short8*)(Bc + ((wc * 4 + cf) * 64 + lane) * 16);
#pragma unroll
    for (int rf = 0; rf < 4; ++rf)
      af[rf] = *(const short8*)(Ac + ((wr * 4 + rf) * 64 + lane) * 16);
#pragma unroll
    for (int rf = 0; rf < 4; ++rf)
#pragma unroll
      for (int cf = 0; cf < 4; ++cf)
        acc[rf][cf] = MFMA16x16x32(af[rf], bfr[cf], acc[rf][cf]);
  }
  __syncthreads();            // k-loop done; smem free for bounce

  // ---- epilogue ----
  if (mode < 2) {
    // y = (relu(acc)+eps)/softplus(s); per-row partials of y^2, y^6
    float sp_inv[4];
#pragma unroll
    for (int cf = 0; cf < 4; ++cf)
      sp_inv[cf] = 1.f / spls[cb + wc * 64 + cf * 16 + cl];
    float p2[4][4], p6[4][4];
#pragma unroll
    for (int rf = 0; rf < 4; ++rf)
#pragma unroll
      for (int j = 0; j < 4; ++j) { p2[rf][j] = 0.f; p6[rf][j] = 0.f; }
#pragma unroll
    for (int rf = 0; rf < 4; ++rf)
#pragma unroll
      for (int cf = 0; cf < 4; ++cf)
#pragma unroll
        for (int j = 0; j < 4; ++j) {
          float v = acc[rf][cf][j];
          v = fmaxf(v, 0.f) + 1e-6f;
          v *= sp_inv[cf];
          acc[rf][cf][j] = v;
          float v2 = v * v;
          p2[rf][j] += v2;
          p6[rf][j] += v2 * v2 * v2;
        }
#pragma unroll
    for (int m = 1; m < 16; m <<= 1) {
#pragma unroll
      for (int rf = 0; rf < 4; ++rf)
#pragma unroll
        for (int j = 0; j < 4; ++j) {
          p2[rf][j] += __shfl_xor(p2[rf][j], m, 64);
          p6[rf][j] += __shfl_xor(p6[rf][j], m, 64);
        }
    }
    if (cl == 0) {
#pragma unroll
      for (int rf = 0; rf < 4; ++rf)
#pragma unroll
        for (int j = 0; j < 4; ++j) {
          int r = wr * 64 + rf * 16 + 4 * g + j;
          pn2[wc][r] = p2[rf][j];
          pn6[wc][r] = p6[rf][j];
        }
    }
    // store y (un-cubed) into 128x256B swizzled bounce
#pragma unroll
    for (int rf = 0; rf < 4; ++rf)
#pragma unroll
      for (int cf = 0; cf < 4; ++cf)
#pragma unroll
        for (int j = 0; j < 4; ++j) {
          int r = wr * 64 + rf * 16 + 4 * g + j;
          int c = wc * 64 + cf * 16 + cl;
          int byteoff = (r * 256 + c * 2) ^ ((r & 7) << 4);
          *(short*)(smem + byteoff) = f2b(acc[rf][cf][j]);
        }
    __syncthreads();
    // per-row atomics (both halves combined)
    if (t < 128) {
      float* g2 = (mode == 0) ? gp2q : gp2k;
      float* g6 = (mode == 0) ? gp6q : gp6k;
      atomicAdd(&g2[rb + t], pn2[0][t] + pn2[1][t]);
      atomicAdd(&g6[rb + t], pn6[0][t] + pn6[1][t]);
    }
    // coalesced y row-major store
    short* ybuf = (mode == 0) ? yq : yk;
#pragma unroll
    for (int i = 0; i < 8; ++i) {
      int chunk = i * 256 + t;          // 0..2047
      int row = chunk >> 4, c16 = chunk & 15;
      int byteoff = (row * 256 + c16 * 16) ^ ((row & 7) << 4);
      short8 v = *(const short8*)(smem + byteoff);
      *(short8*)(ybuf + (size_t)(rb + row) * 512 + cb + c16 * 8) = v;
    }
  } else {
    // v: bounce then k-major fragment pack store
#pragma unroll
    for (int rf = 0; rf < 4; ++rf)
#pragma unroll
      for (int cf = 0; cf < 4; ++cf)
#pragma unroll
        for (int j = 0; j < 4; ++j) {
          int r = wr * 64 + rf * 16 + 4 * g + j;
          int c = wc * 64 + cf * 16 + cl;
          int byteoff = (r * 256 + c * 2) ^ ((r & 7) << 4);
          *(short*)(smem + byteoff) = f2b(acc[rf][cf][j]);
        }
    __syncthreads();
    const int batch = rb >> 12;
    const int jf_base = (rb & 4095) >> 5;
    const int l = lane;
#pragma unroll
    for (int s = 0; s < 8; ++s) {
      int fidx = wid * 8 + s;           // 0..31 = 2 head-halves x 4 cfh x 4 jf
      int hl = fidx >> 4;
      int cfh = (fidx >> 2) & 3;
      int jf = fidx & 3;
      int c = hl * 64 + cfh * 16 + (l & 15);
      int j0 = jf * 32 + 8 * (l >> 4);
      short8 v;
#pragma unroll
      for (int jj = 0; jj < 8; ++jj) {
        int r = j0 + jj;
        int byteoff = (r * 256 + c * 2) ^ ((r & 7) << 4);
        v[jj] = *(const short*)(smem + byteoff);
      }
      int bh = batch * 8 + (cb >> 6) + hl;
      int jfg = jf_base + jf;
      *(short8*)(vpk + (((size_t)(bh * 128 + jfg) * 4 + cfh) * 64 + l) * 8) = v;
    }
  }
}

// ---------------------------------------------------------------------------
// pass2: apply focus cube + renorm from global row-sums, emit final q (row-
// major) and k (frag pack). blocks 0..511: q rows; 512..1023: k rows.
// ---------------------------------------------------------------------------
__global__ __launch_bounds__(256)
void pass2(const short* __restrict__ yq, const short* __restrict__ yk,
           const float* __restrict__ gp2q, const float* __restrict__ gp6q,
           const float* __restrict__ gp2k, const float* __restrict__ gp6k,
           short* __restrict__ qf, short* __restrict__ kpk)
{
  __shared__ char tile[65536];
  __shared__ float facs[64];
  const int t = threadIdx.x;
  const int lane = t & 63;
  const int wid = t >> 6;
  const int bid = blockIdx.x;
  const bool isk = bid >= 512;
  const int rb = (bid & 511) << 6;
  const short* ysrc = isk ? yk : yq;
  const float* g2 = isk ? gp2k : gp2q;
  const float* g6 = isk ? gp6k : gp6q;

  if (t < 64) facs[t] = sqrtf(g2[rb + t] / g6[rb + t]);
  __syncthreads();

  if (!isk) {
    // q: streaming cube * fac -> row-major
#pragma unroll
    for (int i = 0; i < 16; ++i) {
      int chunk = i * 256 + t;          // 0..4095
      int row = chunk >> 6, c8 = chunk & 63;
      short8 v = *(const short8*)(ysrc + (size_t)(rb + row) * 512 + c8 * 8);
      float fac = facs[row];
#pragma unroll
      for (int j = 0; j < 8; ++j) {
        float y = b2f(v[j]);
        v[j] = f2b(y * y * y * fac);
      }
      *(short8*)(qf + (size_t)(rb + row) * 512 + c8 * 8) = v;
    }
  } else {
    // k: cube*fac into swizzled 64x1024B tile, then frag pack
#pragma unroll
    for (int i = 0; i < 16; ++i) {
      int chunk = i * 256 + t;
      int row = chunk >> 6, c8 = chunk & 63;
      short8 v = *(const short8*)(ysrc + (size_t)(rb + row) * 512 + c8 * 8);
      float fac = facs[row];
#pragma unroll
      for (int j = 0; j < 8; ++j) {
        float y = b2f(v[j]);
        v[j] = f2b(y * y * y * fac);
      }
      int byteoff = (row * 1024 + c8 * 16) ^ ((row & 7) << 4);
      *(short8*)(tile + byteoff) = v;
    }
    __syncthreads();
    const int l = lane;
    const int batch = rb >> 12;
    const int jf_base = (rb & 4095) >> 5;
#pragma unroll
    for (int s = 0; s < 16; ++s) {
      int fidx = wid * 16 + s;          // 0..63 = 2 jf x 32 cf
      int jf = fidx >> 5;
      int cf = fidx & 31;
      int c = cf * 16 + (l & 15);
      int j0 = jf * 32 + 8 * (l >> 4);
      short8 v;
#pragma unroll
      for (int jj = 0; jj < 8; ++jj) {
        int j = j0 + jj;
        int byteoff = (j * 1024 + c * 2) ^ ((j & 7) << 4);
        v[jj] = *(const short*)(tile + byteoff);
      }
      int bh = batch * 8 + (cf >> 2);
      int cfh = cf & 3;
      int jfg = jf_base + jf;
      *(short8*)(kpk + (((size_t)(bh * 128 + jfg) * 4 + cfh) * 64 + l) * 8) = v;
    }
  }
}

// ---------------------------------------------------------------------------
// proj (r11): retained for mode 3 only (out = x @ Wp + bp).
// ---------------------------------------------------------------------------
__global__ __launch_bounds__(512, 2)
void proj_kernel(const short* __restrict__ Ax,
                 const short* __restrict__ wpack,
                 const float* __restrict__ bp, float* __restrict__ outf)
{
  __shared__ char smem[65536];          // A-slice dbuf (2x17408B)
  const int t = threadIdx.x;
  const int lane = t & 63;
  const int wid = t >> 6;
  const int g = lane >> 4;
  const int cl = lane & 15;
  const int bid = blockIdx.x;
  const int rb = bid << 6;
  const int sr = t >> 3;
  const int sc = t & 7;
  const int r1 = bid & 3;
  const int r2 = (bid >> 2) & 3;

  const short8* wp8 = (const short8*)(wpack + (size_t)3 * (512 * 512));

  {
    char* dst = smem + sr * 272 + sc * 32;
    const short* src = Ax + (size_t)(rb + sr) * 512 + r1 * 128 + sc * 16;
    *(short8*)dst = *(const short8*)src;
    *(short8*)(dst + 16) = *(const short8*)(src + 8);
  }
  f32x4 zero4 = {0.f, 0.f, 0.f, 0.f};
  f32x4 acc[4][4];
#pragma unroll
  for (int rf = 0; rf < 4; ++rf)
#pragma unroll
    for (int cf = 0; cf < 4; ++cf) acc[rf][cf] = zero4;

  short8 bcur[4], bnxt[4];
  {
    const int kf0 = r1 * 4 + r2;
#pragma unroll
    for (int cf = 0; cf < 4; ++cf)
      bcur[cf] = wp8[((size_t)(kf0 * 32 + wid * 4 + cf)) * 64 + lane];
  }
  BAR_LGKM();

#pragma unroll
  for (int sl = 0; sl < 4; ++sl) {
    const int s_phys = (sl + r1) & 3;
    const int s_next = (s_phys + 1) & 3;
    char* cur = smem + (sl & 1) * 17408;
    short8 rB0, rB1;
    if (sl < 3) {
      const short* src = Ax + (size_t)(rb + sr) * 512 + s_next * 128 + sc * 16;
      rB0 = *(const short8*)src;
      rB1 = *(const short8*)(src + 8);
    }
#pragma unroll
    for (int kl = 0; kl < 4; ++kl) {
      const int k_phys = (kl + r2) & 3;
      const bool last = (sl == 3) && (kl == 3);
      if (!last) {
        const int kf_n = (kl < 3) ? (s_phys * 4 + ((kl + 1 + r2) & 3))
                                  : (((s_phys + 1) & 3) * 4 + r2);
#pragma unroll
        for (int cf = 0; cf < 4; ++cf)
          bnxt[cf] = wp8[((size_t)(kf_n * 32 + wid * 4 + cf)) * 64 + lane];
      }
      short8 af[4];
#pragma unroll
      for (int rf = 0; rf < 4; ++rf)
        af[rf] = *(const short8*)(cur + (rf * 16 + cl) * 272 + k_phys * 64 + 16 * g);
      __builtin_amdgcn_s_setprio(1);
#pragma unroll
      for (int rf = 0; rf < 4; ++rf)
#pragma unroll
        for (int cf = 0; cf < 4; ++cf)
          acc[rf][cf] = MFMA16x16x32(af[rf], bcur[cf], acc[rf][cf]);
      __builtin_amdgcn_s_setprio(0);
      if (!last) {
#pragma unroll
        for (int cf = 0; cf < 4; ++cf) bcur[cf] = bnxt[cf];
      }
    }
    if (sl < 3) {
      char* dst = smem + ((sl + 1) & 1) * 17408 + sr * 272 + sc * 32;
      *(short8*)dst = rB0; *(short8*)(dst + 16) = rB1;
      BAR_LGKM();
    }
  }

#pragma unroll
  for (int rf = 0; rf < 4; ++rf)
#pragma unroll
    for (int cf = 0; cf < 4; ++cf) {
      int c = wid * 64 + cf * 16 + cl;
      float bv = bp[c];
#pragma unroll
      for (int j = 0; j < 4; ++j)
        outf[(size_t)(rb + rf * 16 + 4 * g + j) * 512 + c] = acc[rf][cf][j] + bv;
    }
}

// ---------------------------------------------------------------------------
// kv: block = (bh, split of 512 tokens); 4 waves x 4 jfg chunks each.
// ---------------------------------------------------------------------------
__global__ __launch_bounds__(256)
void kv_kernel(const short* __restrict__ kpack, const short* __restrict__ vpack,
               float* __restrict__ pKV, float* __restrict__ pKS)
{
  __shared__ float red[4][64 * 64];
  __shared__ float ksacc[64];
  const int t = threadIdx.x;
  const int lane = t & 63;
  const int w = t >> 6;
  const int g = lane >> 4;
  const int cl = lane & 15;
  const int bh = blockIdx.x >> 3;
  const int sp = blockIdx.x & 7;
  if (t < 64) ksacc[t] = 0.f;
  __syncthreads();

  f32x4 zero4 = {0.f, 0.f, 0.f, 0.f};
  f32x4 acc[4][4];
#pragma unroll
  for (int df = 0; df < 4; ++df)
#pragma unroll
    for (int cf = 0; cf < 4; ++cf) acc[df][cf] = zero4;
  float ks[4] = {0.f, 0.f, 0.f, 0.f};
  const short8* kp = (const short8*)kpack;
  const short8* vp = (const short8*)vpack;

#pragma unroll
  for (int i = 0; i < 4; ++i) {
    int jfg = sp * 16 + w * 4 + i;
    size_t base = ((size_t)bh * 128 + jfg) * 4 * 64;
    short8 afr[4], bfr[4];
#pragma unroll
    for (int f = 0; f < 4; ++f) {
      afr[f] = vp[base + (size_t)f * 64 + lane];
      bfr[f] = kp[base + (size_t)f * 64 + lane];
    }
#pragma unroll
    for (int cf = 0; cf < 4; ++cf) {
      float s = 0.f;
#pragma unroll
      for (int jj = 0; jj < 8; ++jj) s += b2f(bfr[cf][jj]);
      ks[cf] += s;
    }
#pragma unroll
    for (int df = 0; df < 4; ++df)
#pragma unroll
      for (int cf = 0; cf < 4; ++cf)
        acc[df][cf] = MFMA16x16x32(afr[df], bfr[cf], acc[df][cf]);
  }

#pragma unroll
  for (int cf = 0; cf < 4; ++cf) {
    ks[cf] += __shfl_xor(ks[cf], 16, 64);
    ks[cf] += __shfl_xor(ks[cf], 32, 64);
  }
  if (lane < 16) {
#pragma unroll
    for (int cf = 0; cf < 4; ++cf) atomicAdd(&ksacc[cf * 16 + lane], ks[cf]);
  }

#pragma unroll
  for (int df = 0; df < 4; ++df)
#pragma unroll
    for (int cf = 0; cf < 4; ++cf)
#pragma unroll
      for (int j = 0; j < 4; ++j)
        red[w][(df * 16 + 4 * g + j) * 64 + cf * 16 + cl] = acc[df][cf][j];
  __syncthreads();

  float* dkv = pKV + (size_t)blockIdx.x * 4096;
  for (int i = t; i < 4096; i += 256)
    dkv[i] = red[0][i] + red[1][i] + red[2][i] + red[3][i];
  if (t < 64) pKS[(size_t)blockIdx.x * 64 + t] = ksacc[t];
}

__global__ __launch_bounds__(256)
void kv_reduce(const float* __restrict__ pKV, const float* __restrict__ pKS,
               short* __restrict__ kvT, float* __restrict__ ksum)
{
  const int bh = blockIdx.x;
  const int t = threadIdx.x;
  for (int i = t; i < 4096; i += 256) {
    float s = 0.f;
#pragma unroll
    for (int sp = 0; sp < 8; ++sp) s += pKV[(size_t)(bh * 8 + sp) * 4096 + i];
    kvT[(size_t)bh * 4096 + i] = f2b(s);
  }
  if (t < 64) {
    float s = 0.f;
#pragma unroll
    for (int sp = 0; sp < 8; ++sp) s += pKS[(size_t)(bh * 8 + sp) * 64 + t];
    ksum[bh * 64 + t] = s;
  }
}

// ---------------------------------------------------------------------------
// x: per block (64 rows): z from q.ksum; x = z * q @ kv per head via MFMA;
// x -> swizzled LDS -> row-major bf16 store.
// ---------------------------------------------------------------------------
__global__ __launch_bounds__(512)
void x_kernel(const short* __restrict__ qf, const short* __restrict__ kvT,
              const float* __restrict__ ksum, short* __restrict__ xout)
{
  __shared__ short xt[64 * 512];
  __shared__ float ksb[512];
  __shared__ float zb[64 * 8];
  const int t = threadIdx.x;
  const int lane = t & 63;
  const int wid = t >> 6;
  const int wr = wid >> 1;
  const int wc = wid & 1;
  const int g = lane >> 4;
  const int cl = lane & 15;
  const int rb = blockIdx.x << 6;
  const int batch = rb >> 12;

  ksb[t] = ksum[batch * 512 + t];
  __syncthreads();

  {
    int r = t >> 3, h = t & 7;
    const short8* qrow = (const short8*)(qf + (size_t)(rb + r) * 512 + h * 64);
    float d = 0.f;
#pragma unroll
    for (int c8 = 0; c8 < 8; ++c8) {
      short8 qv = qrow[c8];
#pragma unroll
      for (int jj = 0; jj < 8; ++jj) d += b2f(qv[jj]) * ksb[h * 64 + c8 * 8 + jj];
    }
    zb[r * 8 + h] = 1.f / (d + 1e-6f);
  }
  __syncthreads();

  f32x4 zero4 = {0.f, 0.f, 0.f, 0.f};
  f32x4 xacc[16];
#pragma unroll
  for (int i = 0; i < 16; ++i) xacc[i] = zero4;

  const short8* q8 = (const short8*)qf;
  const size_t qrowbase = (size_t)(rb + wr * 16 + cl) * 64;
#pragma unroll
  for (int hh = 0; hh < 4; ++hh) {
    int h = wc * 4 + hh;
    short8 af0 = q8[qrowbase + h * 8 + g];
    short8 af1 = q8[qrowbase + h * 8 + 4 + g];
    const short8* kv8 = (const short8*)kvT + ((size_t)(batch * 8 + h)) * 512;
#pragma unroll
    for (int nfl = 0; nfl < 4; ++nfl) {
      short8 b0 = kv8[(size_t)(nfl * 16 + cl) * 8 + g];
      short8 b1 = kv8[(size_t)(nfl * 16 + cl) * 8 + 4 + g];
      int nf = hh * 4 + nfl;
      xacc[nf] = MFMA16x16x32(af0, b0, xacc[nf]);
      xacc[nf] = MFMA16x16x32(af1, b1, xacc[nf]);
    }
  }
#pragma unroll
  for (int hh = 0; hh < 4; ++hh) {
    int h = wc * 4 + hh;
    float z4[4];
#pragma unroll
    for (int j = 0; j < 4; ++j) z4[j] = zb[(wr * 16 + 4 * g + j) * 8 + h];
#pragma unroll
    for (int nfl = 0; nfl < 4; ++nfl) {
      int nf = hh * 4 + nfl;
#pragma unroll
      for (int j = 0; j < 4; ++j) {
        float xv = xacc[nf][j] * z4[j];
        int r = wr * 16 + 4 * g + j;
        int c = wc * 256 + nf * 16 + cl;
        int byteoff = (r * 1024 + c * 2) ^ ((r & 7) << 4);
        *(short*)((char*)xt + byteoff) = f2b(xv);
      }
    }
  }
  __syncthreads();

  const int r = t >> 3;
  const int c8 = t & 7;
#pragma unroll
  for (int s = 0; s < 8; ++s) {
    int ci = c8 + 8 * s;
    int byteoff = (r * 1024 + ci * 16) ^ ((r & 7) << 4);
    short8 v = *(const short8*)((const char*)xt + byteoff);
    *(short8*)(xout + (size_t)(rb + r) * 512 + ci * 8) = v;
  }
}

// ---------------------------------------------------------------------------
extern "C" void kernel_launch(void* const* d_in, const int* in_sizes, int n_in,
                              void* d_out, int out_size, void* d_ws, size_t ws_size,
                              hipStream_t stream)
{
  const float* query  = (const float*)d_in[0];
  const float* key_in = (const float*)d_in[1];
  const float* value  = (const float*)d_in[2];
  const float* Wq     = (const float*)d_in[3];
  const float* Wk     = (const float*)d_in[4];
  const float* Wv     = (const float*)d_in[5];
  const float* Wp     = (const float*)d_in[6];
  const float* bp     = (const float*)d_in[7];
  const float* scale  = (const float*)d_in[8];
  float* out = (float*)d_out;

  char* ws = (char*)d_ws;
  size_t off = 0;
  auto alloc = [&](size_t bytes) -> void* {
    void* p = ws + off;
    off += (bytes + 255) & ~(size_t)255;
    return p;
  };
  float* spls  = (float*)alloc(512 * 4);
  short* wpack = (short*)alloc((size_t)4 * 512 * 512 * 2);
  short* qf    = (short*)alloc((size_t)32768 * 512 * 2);
  short* kpack = (short*)alloc((size_t)32768 * 512 * 2);
  short* vpack = (short*)alloc((size_t)32768 * 512 * 2);
  float* pKV   = (float*)alloc((size_t)512 * 4096 * 4);
  float* pKS   = (float*)alloc((size_t)512 * 64 * 4);
  short* kvT   = (short*)alloc((size_t)64 * 4096 * 2);
  float* ksum  = (float*)alloc((size_t)64 * 64 * 4);
  float* gp    = (float*)alloc((size_t)4 * 32768 * 4);   // p2q,p6q,p2k,p6k
  float* gp2q = gp, *gp6q = gp + 32768, *gp2k = gp + 65536, *gp6k = gp + 98304;
  // y scratch lives in d_out (dead until final GEMM overwrites it)
  short* yq = (short*)d_out;
  short* yk = yq + (size_t)32768 * 512;
  // x reuses kpack: kpack is dead after kv_kernel
  short* xbuf  = kpack;

  prep_kernel<<<65, 256, 0, stream>>>(Wq, Wk, Wv, Wp, scale, wpack, spls);
  (void)hipMemsetAsync(gp, 0, (size_t)4 * 32768 * 4, stream);
  gemm128<<<3072, 256, 0, stream>>>(query, key_in, value, wpack, spls,
                                    yq, yk, vpack, gp2q, gp6q, gp2k, gp6k);
  pass2<<<1024, 256, 0, stream>>>(yq, yk, gp2q, gp6q, gp2k, gp6k, qf, kpack);
  kv_kernel<<<512, 256, 0, stream>>>(kpack, vpack, pKV, pKS);
  kv_reduce<<<64, 256, 0, stream>>>(pKV, pKS, kvT, ksum);
  x_kernel<<<512, 512, 0, stream>>>(qf, kvT, ksum, xbuf);
  proj_kernel<<<512, 512, 0, stream>>>(xbuf, wpack, bp, out);
}